// Round 4
// baseline (5351.657 us; speedup 1.0000x reference)
//
#include <hip/hip_runtime.h>
#include <hip/hip_bf16.h>

#define B_  2
#define T_  2048
#define H_  2048
#define NH_ 16
#define HD_ 128

// Y[M,N] = A[M,K] @ W[N,K]^T   (torch Linear: y = x @ W.T), all fp32.
__global__ __launch_bounds__(256) void gemm_bt(
    const float* __restrict__ A, const float* __restrict__ W,
    float* __restrict__ Y, int M, int N, int K)
{
    // [kk][m] layout, padded 64->66 to break bank conflicts on the transposed store
    __shared__ float As[16][66];
    __shared__ float Bs[16][66];

    const int tx = threadIdx.x & 15;   // -> 4 output cols
    const int ty = threadIdx.x >> 4;   // -> 4 output rows
    const int m0 = blockIdx.y * 64;
    const int n0 = blockIdx.x * 64;

    const int lrow = threadIdx.x >> 2;        // 0..63
    const int kg   = (threadIdx.x & 3) * 4;   // 0,4,8,12

    float acc[4][4];
    #pragma unroll
    for (int i = 0; i < 4; i++)
        #pragma unroll
        for (int j = 0; j < 4; j++) acc[i][j] = 0.f;

    for (int k0 = 0; k0 < K; k0 += 16) {
        float4 av = *(const float4*)(A + (size_t)(m0 + lrow) * K + k0 + kg);
        float4 bv = *(const float4*)(W + (size_t)(n0 + lrow) * K + k0 + kg);
        __syncthreads();
        As[kg + 0][lrow] = av.x; As[kg + 1][lrow] = av.y;
        As[kg + 2][lrow] = av.z; As[kg + 3][lrow] = av.w;
        Bs[kg + 0][lrow] = bv.x; Bs[kg + 1][lrow] = bv.y;
        Bs[kg + 2][lrow] = bv.z; Bs[kg + 3][lrow] = bv.w;
        __syncthreads();
        #pragma unroll
        for (int kk = 0; kk < 16; kk++) {
            float a0 = As[kk][ty * 4 + 0], a1 = As[kk][ty * 4 + 1];
            float a2 = As[kk][ty * 4 + 2], a3 = As[kk][ty * 4 + 3];
            float b0 = Bs[kk][tx * 4 + 0], b1 = Bs[kk][tx * 4 + 1];
            float b2 = Bs[kk][tx * 4 + 2], b3 = Bs[kk][tx * 4 + 3];
            acc[0][0] += a0 * b0; acc[0][1] += a0 * b1; acc[0][2] += a0 * b2; acc[0][3] += a0 * b3;
            acc[1][0] += a1 * b0; acc[1][1] += a1 * b1; acc[1][2] += a1 * b2; acc[1][3] += a1 * b3;
            acc[2][0] += a2 * b0; acc[2][1] += a2 * b1; acc[2][2] += a2 * b2; acc[2][3] += a2 * b3;
            acc[3][0] += a3 * b0; acc[3][1] += a3 * b1; acc[3][2] += a3 * b2; acc[3][3] += a3 * b3;
        }
    }

    #pragma unroll
    for (int i = 0; i < 4; i++) {
        const size_t row = m0 + ty * 4 + i;
        #pragma unroll
        for (int j = 0; j < 4; j++) {
            const size_t col = n0 + tx * 4 + j;
            Y[row * N + col] = acc[i][j];
        }
    }
}

// RoPE in-place on q and k. One thread handles the (d, d+64) pair of one head.
__global__ __launch_bounds__(256) void rope_qk(
    float* __restrict__ q, float* __restrict__ kk,
    const float* __restrict__ cosp, const float* __restrict__ sinp)
{
    const int idx  = blockIdx.x * 256 + threadIdx.x;  // B*T*NH*64 threads
    const int d    = idx & 63;
    const int rest = idx >> 6;
    const int h    = rest & (NH_ - 1);
    const int bt   = rest >> 4;           // NH_ == 16
    const int t    = bt & (T_ - 1);
    const size_t base = (size_t)bt * H_ + h * HD_;

    const float c0 = cosp[t * HD_ + d],      s0 = sinp[t * HD_ + d];
    const float c1 = cosp[t * HD_ + d + 64], s1 = sinp[t * HD_ + d + 64];

    float q0 = q[base + d], q1 = q[base + d + 64];
    q[base + d]      = q0 * c0 - q1 * s0;
    q[base + d + 64] = q1 * c1 + q0 * s1;

    float k0 = kk[base + d], k1 = kk[base + d + 64];
    kk[base + d]      = k0 * c0 - k1 * s0;
    kk[base + d + 64] = k1 * c1 + k0 * s1;
}

// Flash-style causal attention, fp32.
// Block = 256 threads = 4 waves; wave w owns q-row r = blockIdx.x*4 + w.
__global__ __launch_bounds__(256) void attn_fwd(
    const float* __restrict__ q, const float* __restrict__ k,
    const float* __restrict__ v, float* __restrict__ o)
{
    __shared__ float Ks[64][132];
    __shared__ float Vs[64][128];
    __shared__ float Qs[4][128];

    const int lane = threadIdx.x & 63;
    const int w    = threadIdx.x >> 6;
    const int b    = blockIdx.z, h = blockIdx.y;
    const int r    = blockIdx.x * 4 + w;
    const float scale = 0.08838834764831845f;  // 1/sqrt(128)

    const size_t qbase  = ((size_t)b * T_ + r) * H_ + h * HD_;
    const size_t kvbase = (size_t)b * T_ * H_ + h * HD_;

    Qs[w][lane]      = q[qbase + lane] * scale;
    Qs[w][lane + 64] = q[qbase + lane + 64] * scale;

    float m = -__builtin_inff(), l = 0.f, acc0 = 0.f, acc1 = 0.f;
    const int ntiles = (blockIdx.x * 4 + 3) / 64 + 1;  // uniform across block

    for (int tile = 0; tile < ntiles; tile++) {
        __syncthreads();
        const int kt0 = tile * 64;
        for (int idx = threadIdx.x; idx < 64 * 128; idx += 256) {
            const int row = idx >> 7, col = idx & 127;
            const size_t g = kvbase + (size_t)(kt0 + row) * H_ + col;
            Ks[row][col] = k[g];
            Vs[row][col] = v[g];
        }
        __syncthreads();

        float s = 0.f;
        #pragma unroll
        for (int d = 0; d < 128; d++) s += Qs[w][d] * Ks[lane][d];
        if (kt0 + lane > r) s = -__builtin_inff();   // causal mask

        float tmax = s;
        #pragma unroll
        for (int off = 32; off > 0; off >>= 1) tmax = fmaxf(tmax, __shfl_xor(tmax, off));
        const float mnew  = fmaxf(m, tmax);
        const float alpha = __expf(m - mnew);        // tile 0: exp(-inf) = 0
        const float p     = __expf(s - mnew);        // masked: exp(-inf) = 0

        float psum = p;
        #pragma unroll
        for (int off = 32; off > 0; off >>= 1) psum += __shfl_xor(psum, off);
        l = l * alpha + psum;
        acc0 *= alpha; acc1 *= alpha;

        for (int j = 0; j < 64; j++) {
            const float pj = __shfl(p, j);
            acc0 += pj * Vs[j][lane];
            acc1 += pj * Vs[j][lane + 64];
        }
        m = mnew;
    }

    const float inv = 1.f / l;
    o[qbase + lane]      = acc0 * inv;   // [B,T,NH,HD] flattened == [B,T,H]
    o[qbase + lane + 64] = acc1 * inv;
}

extern "C" void kernel_launch(void* const* d_in, const int* in_sizes, int n_in,
                              void* d_out, int out_size, void* d_ws, size_t ws_size,
                              hipStream_t stream)
{
    const float* x    = (const float*)d_in[0];
    const float* cosp = (const float*)d_in[1];
    const float* sinp = (const float*)d_in[2];
    const float* Wq   = (const float*)d_in[3];
    const float* Wk   = (const float*)d_in[4];
    const float* Wv   = (const float*)d_in[5];
    const float* Wo   = (const float*)d_in[6];

    const size_t NEL = (size_t)B_ * T_ * H_;   // 8388608 floats per buffer
    float* qbuf = (float*)d_ws;
    float* kbuf = qbuf + NEL;
    float* vbuf = kbuf + NEL;
    float* abuf = vbuf + NEL;                  // attention output, pre-Wo

    const int M = B_ * T_, N = H_, K = H_;
    dim3 gg(N / 64, M / 64);

    gemm_bt<<<gg, 256, 0, stream>>>(x, Wq, qbuf, M, N, K);
    gemm_bt<<<gg, 256, 0, stream>>>(x, Wk, kbuf, M, N, K);
    gemm_bt<<<gg, 256, 0, stream>>>(x, Wv, vbuf, M, N, K);

    rope_qk<<<(B_ * T_ * NH_ * 64) / 256, 256, 0, stream>>>(qbuf, kbuf, cosp, sinp);

    attn_fwd<<<dim3(T_ / 4, NH_, B_), 256, 0, stream>>>(qbuf, kbuf, vbuf, abuf);

    gemm_bt<<<gg, 256, 0, stream>>>(abuf, Wo, (float*)d_out, M, N, K);
}

// Round 5
// 2517.198 us; speedup vs baseline: 2.1260x; 2.1260x over previous
//
#include <hip/hip_runtime.h>
#include <hip/hip_bf16.h>

#define B_  2
#define T_  2048
#define H_  2048
#define NH_ 16
#define HD_ 128

typedef __attribute__((ext_vector_type(8))) short  short8;   // 8 bf16 in 4 VGPRs
typedef __attribute__((ext_vector_type(4))) float  floatx4;  // MFMA C/D

__device__ __forceinline__ unsigned short f2bf(float x) {
    union { float f; unsigned int u; } c; c.f = x;
    unsigned int r = c.u + 0x7FFF + ((c.u >> 16) & 1);   // RNE
    return (unsigned short)(r >> 16);
}

// ---------------- fp32 GEMM: Y[M,N] = A[M,K] @ W[N,K]^T (unchanged, verified) ----
__global__ __launch_bounds__(256) void gemm_bt(
    const float* __restrict__ A, const float* __restrict__ W,
    float* __restrict__ Y, int M, int N, int K)
{
    __shared__ float As[16][66];
    __shared__ float Bs[16][66];

    const int tx = threadIdx.x & 15;
    const int ty = threadIdx.x >> 4;
    const int m0 = blockIdx.y * 64;
    const int n0 = blockIdx.x * 64;
    const int lrow = threadIdx.x >> 2;
    const int kg   = (threadIdx.x & 3) * 4;

    float acc[4][4];
    #pragma unroll
    for (int i = 0; i < 4; i++)
        #pragma unroll
        for (int j = 0; j < 4; j++) acc[i][j] = 0.f;

    for (int k0 = 0; k0 < K; k0 += 16) {
        float4 av = *(const float4*)(A + (size_t)(m0 + lrow) * K + k0 + kg);
        float4 bv = *(const float4*)(W + (size_t)(n0 + lrow) * K + k0 + kg);
        __syncthreads();
        As[kg + 0][lrow] = av.x; As[kg + 1][lrow] = av.y;
        As[kg + 2][lrow] = av.z; As[kg + 3][lrow] = av.w;
        Bs[kg + 0][lrow] = bv.x; Bs[kg + 1][lrow] = bv.y;
        Bs[kg + 2][lrow] = bv.z; Bs[kg + 3][lrow] = bv.w;
        __syncthreads();
        #pragma unroll
        for (int kk = 0; kk < 16; kk++) {
            float a0 = As[kk][ty*4+0], a1 = As[kk][ty*4+1];
            float a2 = As[kk][ty*4+2], a3 = As[kk][ty*4+3];
            float b0 = Bs[kk][tx*4+0], b1 = Bs[kk][tx*4+1];
            float b2 = Bs[kk][tx*4+2], b3 = Bs[kk][tx*4+3];
            acc[0][0]+=a0*b0; acc[0][1]+=a0*b1; acc[0][2]+=a0*b2; acc[0][3]+=a0*b3;
            acc[1][0]+=a1*b0; acc[1][1]+=a1*b1; acc[1][2]+=a1*b2; acc[1][3]+=a1*b3;
            acc[2][0]+=a2*b0; acc[2][1]+=a2*b1; acc[2][2]+=a2*b2; acc[2][3]+=a2*b3;
            acc[3][0]+=a3*b0; acc[3][1]+=a3*b1; acc[3][2]+=a3*b2; acc[3][3]+=a3*b3;
        }
    }
    #pragma unroll
    for (int i = 0; i < 4; i++) {
        const size_t row = m0 + ty * 4 + i;
        #pragma unroll
        for (int j = 0; j < 4; j++)
            Y[row * N + (n0 + tx * 4 + j)] = acc[i][j];
    }
}

// ---------------- RoPE + bf16 convert: fp32 [B,T,H] -> bf16 [BH][T][HD] ----------
// q additionally scaled by 1/sqrt(HD).
__global__ __launch_bounds__(256) void rope_convert_qk(
    const float* __restrict__ qb, const float* __restrict__ kb,
    const float* __restrict__ cosp, const float* __restrict__ sinp,
    unsigned short* __restrict__ qh, unsigned short* __restrict__ kh)
{
    const int idx  = blockIdx.x * 256 + threadIdx.x;
    const int d    = idx & 63;
    const int rest = idx >> 6;
    const int h    = rest & 15;
    const int bt   = rest >> 4;
    const int t    = bt & (T_ - 1);
    const int b    = bt >> 11;                       // T_ = 2048
    const size_t ibase = (size_t)bt * H_ + h * HD_;
    const size_t obase = (((size_t)b * NH_ + h) * T_ + t) * HD_;

    const float c0 = cosp[t*HD_ + d],      s0 = sinp[t*HD_ + d];
    const float c1 = cosp[t*HD_ + d + 64], s1 = sinp[t*HD_ + d + 64];
    const float sc = 0.08838834764831845f;           // 1/sqrt(128)

    float q0 = qb[ibase + d], q1 = qb[ibase + d + 64];
    qh[obase + d]      = f2bf((q0*c0 - q1*s0) * sc);
    qh[obase + d + 64] = f2bf((q1*c1 + q0*s1) * sc);

    float k0 = kb[ibase + d], k1 = kb[ibase + d + 64];
    kh[obase + d]      = f2bf(k0*c0 - k1*s0);
    kh[obase + d + 64] = f2bf(k1*c1 + k0*s1);
}

// ---------------- V transpose + convert: fp32 [B,T,H] -> bf16 [BH][HD][T] --------
__global__ __launch_bounds__(256) void transpose_v(
    const float* __restrict__ vb, unsigned short* __restrict__ vh)
{
    __shared__ float tile[64][65];
    const int t0 = blockIdx.x * 64;
    const int d0 = blockIdx.y * 64;
    const int bh = blockIdx.z;
    const int b  = bh >> 4, h = bh & 15;

    for (int i = threadIdx.x; i < 4096; i += 256) {
        int r = i >> 6, c = i & 63;
        tile[r][c] = vb[((size_t)b*T_ + t0 + r) * H_ + h*HD_ + d0 + c];
    }
    __syncthreads();
    for (int i = threadIdx.x; i < 4096; i += 256) {
        int dr = i >> 6, tc = i & 63;
        vh[((size_t)bh * HD_ + d0 + dr) * T_ + t0 + tc] = f2bf(tile[tc][dr]);
    }
}

// ---------------- MFMA flash attention ------------------------------------------
// Block: 256 thr = 4 waves; wave w owns q-rows qblk*64 + w*16 .. +15.
// KV tiles of 64 keys staged in LDS; 16x16x32 bf16 MFMA.
// Fragment layouts (verified, learn_hip m89/m120):
//   A[m=lane&15][k=quad*8+j], B[k=quad*8+j][n=lane&15], C/D: col=lane&15, row=quad*4+reg
#define LDS_KROW 136   // 128+8 bf16, breaks bank pileup on row-indexed b128 reads
#define LDS_VROW 72    // 64+8
#define LDS_PROW 72

__global__ __launch_bounds__(256) void attn_mfma(
    const unsigned short* __restrict__ qh,   // [BH][T][HD]  (pre-scaled)
    const unsigned short* __restrict__ kh,   // [BH][T][HD]
    const unsigned short* __restrict__ vh,   // [BH][HD][T]  (transposed)
    float* __restrict__ o)                   // [B][T][H] fp32
{
    __shared__ __attribute__((aligned(16))) unsigned short Ks[64 * LDS_KROW];
    __shared__ __attribute__((aligned(16))) unsigned short Vs[128 * LDS_VROW];
    __shared__ __attribute__((aligned(16))) unsigned short Ps[4][16 * LDS_PROW];

    const int tid  = threadIdx.x;
    const int lane = tid & 63;
    const int w    = tid >> 6;
    const int n16  = lane & 15;
    const int quad = lane >> 4;
    const int bh   = blockIdx.y;
    const int qblk = blockIdx.x;
    const int q0w  = qblk * 64 + w * 16;

    // Q A-fragments, 4 k-chunks of 32
    short8 qf[4];
    {
        const size_t qbase = ((size_t)bh * T_ + q0w + n16) * HD_ + quad * 8;
        #pragma unroll
        for (int c = 0; c < 4; c++)
            qf[c] = *(const short8*)(qh + qbase + c * 32);
    }

    floatx4 of[8];
    #pragma unroll
    for (int i = 0; i < 8; i++) of[i] = (floatx4){0.f, 0.f, 0.f, 0.f};
    float mrow[4], lrow[4];
    #pragma unroll
    for (int r = 0; r < 4; r++) { mrow[r] = -INFINITY; lrow[r] = 0.f; }

    const int nkv = qblk + 1;
    for (int kv = 0; kv < nkv; kv++) {
        const int kv0 = kv * 64;
        __syncthreads();
        // stage K [64 keys][128 d]
        {
            const size_t gk = ((size_t)bh * T_ + kv0) * HD_;
            #pragma unroll
            for (int it = 0; it < 4; it++) {
                int i = tid + it * 256;
                int row = i >> 4, c8 = (i & 15) * 8;
                *(short8*)(Ks + row * LDS_KROW + c8) =
                    *(const short8*)(kh + gk + (size_t)row * HD_ + c8);
            }
            // stage V^T [128 d][64 keys]
            const size_t gv = (size_t)bh * HD_ * T_ + kv0;
            #pragma unroll
            for (int it = 0; it < 4; it++) {
                int i = tid + it * 256;
                int d = i >> 3, k8 = (i & 7) * 8;
                *(short8*)(Vs + d * LDS_VROW + k8) =
                    *(const short8*)(vh + gv + (size_t)d * T_ + k8);
            }
        }
        __syncthreads();

        // S = Q K^T : 4 tiles of 16x16 (key-groups kg)
        floatx4 s[4];
        #pragma unroll
        for (int kg = 0; kg < 4; kg++) {
            floatx4 acc = {0.f, 0.f, 0.f, 0.f};
            #pragma unroll
            for (int c = 0; c < 4; c++) {
                short8 kf = *(const short8*)(Ks + (kg*16 + n16) * LDS_KROW + c*32 + quad*8);
                acc = __builtin_amdgcn_mfma_f32_16x16x32_bf16(qf[c], kf, acc, 0, 0, 0);
            }
            s[kg] = acc;
        }

        // causal mask + online softmax; P -> LDS (bf16, A-layout rows)
        float alpha[4];
        #pragma unroll
        for (int r = 0; r < 4; r++) {
            const int qrow = q0w + quad * 4 + r;
            float v0 = s[0][r], v1 = s[1][r], v2 = s[2][r], v3 = s[3][r];
            if (kv0 +  0 + n16 > qrow) v0 = -INFINITY;
            if (kv0 + 16 + n16 > qrow) v1 = -INFINITY;
            if (kv0 + 32 + n16 > qrow) v2 = -INFINITY;
            if (kv0 + 48 + n16 > qrow) v3 = -INFINITY;

            float tm = fmaxf(fmaxf(v0, v1), fmaxf(v2, v3));
            tm = fmaxf(tm, __shfl_xor(tm, 1));
            tm = fmaxf(tm, __shfl_xor(tm, 2));
            tm = fmaxf(tm, __shfl_xor(tm, 4));
            tm = fmaxf(tm, __shfl_xor(tm, 8));

            const float mnew = fmaxf(mrow[r], tm);
            const float a    = __expf(mrow[r] - mnew);
            const float p0 = __expf(v0 - mnew), p1 = __expf(v1 - mnew);
            const float p2 = __expf(v2 - mnew), p3 = __expf(v3 - mnew);

            float ts = p0 + p1 + p2 + p3;
            ts += __shfl_xor(ts, 1);
            ts += __shfl_xor(ts, 2);
            ts += __shfl_xor(ts, 4);
            ts += __shfl_xor(ts, 8);

            lrow[r] = lrow[r] * a + ts;
            mrow[r] = mnew;
            alpha[r] = a;

            const int prow = (quad * 4 + r) * LDS_PROW;
            Ps[w][prow + n16 +  0] = f2bf(p0);
            Ps[w][prow + n16 + 16] = f2bf(p1);
            Ps[w][prow + n16 + 32] = f2bf(p2);
            Ps[w][prow + n16 + 48] = f2bf(p3);
        }
        #pragma unroll
        for (int nt = 0; nt < 8; nt++)
            #pragma unroll
            for (int r = 0; r < 4; r++) of[nt][r] *= alpha[r];

        // O += P V : P A-frags from LDS (per-wave region, wave-internal ordering)
        short8 pf0 = *(const short8*)(&Ps[w][n16 * LDS_PROW + quad * 8]);
        short8 pf1 = *(const short8*)(&Ps[w][n16 * LDS_PROW + 32 + quad * 8]);
        #pragma unroll
        for (int nt = 0; nt < 8; nt++) {
            short8 vf0 = *(const short8*)(Vs + (nt*16 + n16) * LDS_VROW + quad * 8);
            short8 vf1 = *(const short8*)(Vs + (nt*16 + n16) * LDS_VROW + 32 + quad * 8);
            of[nt] = __builtin_amdgcn_mfma_f32_16x16x32_bf16(pf0, vf0, of[nt], 0, 0, 0);
            of[nt] = __builtin_amdgcn_mfma_f32_16x16x32_bf16(pf1, vf1, of[nt], 0, 0, 0);
        }
    }

    // epilogue: divide by l, store fp32 [B,T,H]
    const int b = bh >> 4, h = bh & 15;
    #pragma unroll
    for (int r = 0; r < 4; r++) {
        const float inv = 1.f / lrow[r];
        const size_t orow = ((size_t)b * T_ + q0w + quad*4 + r) * H_ + h * HD_;
        #pragma unroll
        for (int nt = 0; nt < 8; nt++)
            o[orow + nt*16 + n16] = of[nt][r] * inv;
    }
}

extern "C" void kernel_launch(void* const* d_in, const int* in_sizes, int n_in,
                              void* d_out, int out_size, void* d_ws, size_t ws_size,
                              hipStream_t stream)
{
    const float* x    = (const float*)d_in[0];
    const float* cosp = (const float*)d_in[1];
    const float* sinp = (const float*)d_in[2];
    const float* Wq   = (const float*)d_in[3];
    const float* Wk   = (const float*)d_in[4];
    const float* Wv   = (const float*)d_in[5];
    const float* Wo   = (const float*)d_in[6];

    const size_t NEL = (size_t)B_ * T_ * H_;   // 8388608
    const size_t NB  = NEL * 4;                // bytes per fp32 buffer
    char* ws = (char*)d_ws;

    // overlay plan (total 4*NB = 134 MB, same footprint as round 4):
    //   [0,NB)      qbuf f32   -> later vh bf16 (qbuf dead)
    //   [NB,2NB)    kbuf f32   -> later attbuf f32 (kbuf dead)
    //   [2NB,3NB)   vbuf f32
    //   [3NB,3.5NB) qh bf16, [3.5NB,4NB) kh bf16
    float* qbuf = (float*)ws;
    float* kbuf = (float*)(ws + NB);
    float* vbuf = (float*)(ws + 2*NB);
    unsigned short* qh = (unsigned short*)(ws + 3*NB);
    unsigned short* kh = (unsigned short*)(ws + 3*NB + NB/2);
    unsigned short* vh = (unsigned short*)ws;        // overlays dead qbuf
    float* attbuf = (float*)(ws + NB);               // overlays dead kbuf

    const int M = B_ * T_, N = H_, K = H_;
    dim3 gg(N / 64, M / 64);

    gemm_bt<<<gg, 256, 0, stream>>>(x, Wq, qbuf, M, N, K);
    gemm_bt<<<gg, 256, 0, stream>>>(x, Wk, kbuf, M, N, K);
    gemm_bt<<<gg, 256, 0, stream>>>(x, Wv, vbuf, M, N, K);

    rope_convert_qk<<<(B_*T_*NH_*64)/256, 256, 0, stream>>>(qbuf, kbuf, cosp, sinp, qh, kh);
    transpose_v<<<dim3(T_/64, HD_/64, B_*NH_), 256, 0, stream>>>(vbuf, vh);

    attn_mfma<<<dim3(T_/64, B_*NH_), 256, 0, stream>>>(qh, kh, vh, attbuf);

    gemm_bt<<<gg, 256, 0, stream>>>(attbuf, Wo, (float*)d_out, M, N, K);
}

// Round 6
// 665.364 us; speedup vs baseline: 8.0432x; 3.7832x over previous
//
#include <hip/hip_runtime.h>
#include <hip/hip_bf16.h>

#define B_  2
#define T_  2048
#define H_  2048
#define NH_ 16
#define HD_ 128

typedef __attribute__((ext_vector_type(8))) short  short8;   // 8 bf16 in 4 VGPRs
typedef __attribute__((ext_vector_type(4))) float  floatx4;  // MFMA C/D

__device__ __forceinline__ unsigned short f2bf(float x) {
    union { float f; unsigned int u; } c; c.f = x;
    unsigned int r = c.u + 0x7FFF + ((c.u >> 16) & 1);   // RNE
    return (unsigned short)(r >> 16);
}
__device__ __forceinline__ float bf2f(unsigned short u) {
    union { float f; unsigned int i; } c;
    c.i = ((unsigned int)u) << 16;
    return c.f;
}

// async global->LDS, 16B per lane; LDS dest is wave-uniform base + lane*16
__device__ __forceinline__ void gload_lds16(const void* g, void* l) {
    __builtin_amdgcn_global_load_lds(
        (__attribute__((address_space(1))) void*)g,
        (__attribute__((address_space(3))) void*)l, 16, 0, 0);
}

// ---------------- fp32 -> bf16 convert (vector4) ---------------------------------
__global__ __launch_bounds__(256) void f32_to_bf16(
    const float* __restrict__ src, unsigned short* __restrict__ dst, int n)
{
    const int i = (blockIdx.x * 256 + threadIdx.x) * 4;
    if (i < n) {
        float4 v = *(const float4*)(src + i);
        ushort4 o;
        o.x = f2bf(v.x); o.y = f2bf(v.y); o.z = f2bf(v.z); o.w = f2bf(v.w);
        *(ushort4*)(dst + i) = o;
    }
}

// ---------------- bf16 MFMA GEMM: Y[M,N] = A[M,K] @ W[N,K]^T ---------------------
// m97 structure: 128x128 tile, BK=32, global_load_lds(16B), 4 waves x 4x4 MFMA tiles.
template<bool BF16_OUT>
__global__ __launch_bounds__(256) void gemm_mfma(
    const unsigned short* __restrict__ A,   // [M,K] bf16
    const unsigned short* __restrict__ W,   // [N,K] bf16
    float* __restrict__ Yf, unsigned short* __restrict__ Yb,
    int M, int N, int K)
{
    __shared__ __attribute__((aligned(16))) unsigned short Ah[128 * 32];
    __shared__ __attribute__((aligned(16))) unsigned short Bh[128 * 32];

    const int tid  = threadIdx.x;
    const int lane = tid & 63;
    const int n16  = lane & 15;
    const int quad = lane >> 4;
    const int w    = tid >> 6;
    const int wm   = w & 1, wn = w >> 1;

    const int m0 = blockIdx.y * 128;
    const int n0 = blockIdx.x * 128;

    const int srow = tid >> 2;          // staging row 0..63
    const int scol = (tid & 3) * 8;     // staging k-offset (bf16 units)

    floatx4 acc[4][4];
    #pragma unroll
    for (int i = 0; i < 4; i++)
        #pragma unroll
        for (int j = 0; j < 4; j++) acc[i][j] = (floatx4){0.f, 0.f, 0.f, 0.f};

    for (int k0 = 0; k0 < K; k0 += 32) {
        __syncthreads();
        gload_lds16(A + (size_t)(m0 +      srow) * K + k0 + scol, Ah + (size_t)tid * 8);
        gload_lds16(A + (size_t)(m0 + 64 + srow) * K + k0 + scol, Ah + (size_t)(tid + 256) * 8);
        gload_lds16(W + (size_t)(n0 +      srow) * K + k0 + scol, Bh + (size_t)tid * 8);
        gload_lds16(W + (size_t)(n0 + 64 + srow) * K + k0 + scol, Bh + (size_t)(tid + 256) * 8);
        __syncthreads();   // compiler drains vmcnt before s_barrier

        short8 af[4], bfr[4];
        #pragma unroll
        for (int i = 0; i < 4; i++) {
            af[i]  = *(const short8*)(Ah + (wm * 64 + i * 16 + n16) * 32 + quad * 8);
            bfr[i] = *(const short8*)(Bh + (wn * 64 + i * 16 + n16) * 32 + quad * 8);
        }
        #pragma unroll
        for (int i = 0; i < 4; i++)
            #pragma unroll
            for (int j = 0; j < 4; j++)
                acc[i][j] = __builtin_amdgcn_mfma_f32_16x16x32_bf16(af[i], bfr[j], acc[i][j], 0, 0, 0);
    }

    // C/D: col = lane&15, row = quad*4 + reg  (verified m89/m91)
    #pragma unroll
    for (int i = 0; i < 4; i++) {
        const int rbase = m0 + wm * 64 + i * 16 + quad * 4;
        #pragma unroll
        for (int r = 0; r < 4; r++) {
            const size_t row = rbase + r;
            #pragma unroll
            for (int j = 0; j < 4; j++) {
                const size_t col = n0 + wn * 64 + j * 16 + n16;
                if (BF16_OUT) Yb[row * N + col] = f2bf(acc[i][j][r]);
                else          Yf[row * N + col] = acc[i][j][r];
            }
        }
    }
}

// ---------------- RoPE: bf16 [B,T,H] -> bf16 [BH][T][HD] (q scaled) --------------
__global__ __launch_bounds__(256) void rope_convert_qk(
    const unsigned short* __restrict__ qp, const unsigned short* __restrict__ kp,
    const float* __restrict__ cosp, const float* __restrict__ sinp,
    unsigned short* __restrict__ qh, unsigned short* __restrict__ kh)
{
    const int idx  = blockIdx.x * 256 + threadIdx.x;
    const int d    = idx & 63;
    const int rest = idx >> 6;
    const int h    = rest & 15;
    const int bt   = rest >> 4;
    const int t    = bt & (T_ - 1);
    const int b    = bt >> 11;                       // T_ = 2048
    const size_t ibase = (size_t)bt * H_ + h * HD_;
    const size_t obase = (((size_t)b * NH_ + h) * T_ + t) * HD_;

    const float c0 = cosp[t*HD_ + d],      s0 = sinp[t*HD_ + d];
    const float c1 = cosp[t*HD_ + d + 64], s1 = sinp[t*HD_ + d + 64];
    const float sc = 0.08838834764831845f;           // 1/sqrt(128)

    float q0 = bf2f(qp[ibase + d]), q1 = bf2f(qp[ibase + d + 64]);
    qh[obase + d]      = f2bf((q0*c0 - q1*s0) * sc);
    qh[obase + d + 64] = f2bf((q1*c1 + q0*s1) * sc);

    float k0 = bf2f(kp[ibase + d]), k1 = bf2f(kp[ibase + d + 64]);
    kh[obase + d]      = f2bf(k0*c0 - k1*s0);
    kh[obase + d + 64] = f2bf(k1*c1 + k0*s1);
}

// ---------------- V transpose: bf16 [B,T,H] -> bf16 [BH][HD][T] ------------------
__global__ __launch_bounds__(256) void transpose_v(
    const unsigned short* __restrict__ vb, unsigned short* __restrict__ vh)
{
    __shared__ float tile[64][65];
    const int t0 = blockIdx.x * 64;
    const int d0 = blockIdx.y * 64;
    const int bh = blockIdx.z;
    const int b  = bh >> 4, h = bh & 15;

    for (int i = threadIdx.x; i < 4096; i += 256) {
        int r = i >> 6, c = i & 63;
        tile[r][c] = bf2f(vb[((size_t)b*T_ + t0 + r) * H_ + h*HD_ + d0 + c]);
    }
    __syncthreads();
    for (int i = threadIdx.x; i < 4096; i += 256) {
        int dr = i >> 6, tc = i & 63;
        vh[((size_t)bh * HD_ + d0 + dr) * T_ + t0 + tc] = f2bf(tile[tc][dr]);  // exact round-trip
    }
}

// ---------------- MFMA flash attention (round-5 verified; bf16 epilogue) ---------
#define LDS_KROW 136
#define LDS_VROW 72
#define LDS_PROW 72

__global__ __launch_bounds__(256) void attn_mfma(
    const unsigned short* __restrict__ qh,   // [BH][T][HD] (pre-scaled)
    const unsigned short* __restrict__ kh,   // [BH][T][HD]
    const unsigned short* __restrict__ vh,   // [BH][HD][T]
    unsigned short* __restrict__ o)          // [B][T][H] bf16
{
    __shared__ __attribute__((aligned(16))) unsigned short Ks[64 * LDS_KROW];
    __shared__ __attribute__((aligned(16))) unsigned short Vs[128 * LDS_VROW];
    __shared__ __attribute__((aligned(16))) unsigned short Ps[4][16 * LDS_PROW];

    const int tid  = threadIdx.x;
    const int lane = tid & 63;
    const int w    = tid >> 6;
    const int n16  = lane & 15;
    const int quad = lane >> 4;
    const int bh   = blockIdx.y;
    const int qblk = blockIdx.x;
    const int q0w  = qblk * 64 + w * 16;

    short8 qf[4];
    {
        const size_t qbase = ((size_t)bh * T_ + q0w + n16) * HD_ + quad * 8;
        #pragma unroll
        for (int c = 0; c < 4; c++)
            qf[c] = *(const short8*)(qh + qbase + c * 32);
    }

    floatx4 of[8];
    #pragma unroll
    for (int i = 0; i < 8; i++) of[i] = (floatx4){0.f, 0.f, 0.f, 0.f};
    float mrow[4], lrow[4];
    #pragma unroll
    for (int r = 0; r < 4; r++) { mrow[r] = -INFINITY; lrow[r] = 0.f; }

    const int nkv = qblk + 1;
    for (int kv = 0; kv < nkv; kv++) {
        const int kv0 = kv * 64;
        __syncthreads();
        {
            const size_t gk = ((size_t)bh * T_ + kv0) * HD_;
            #pragma unroll
            for (int it = 0; it < 4; it++) {
                int i = tid + it * 256;
                int row = i >> 4, c8 = (i & 15) * 8;
                *(short8*)(Ks + row * LDS_KROW + c8) =
                    *(const short8*)(kh + gk + (size_t)row * HD_ + c8);
            }
            const size_t gv = (size_t)bh * HD_ * T_ + kv0;
            #pragma unroll
            for (int it = 0; it < 4; it++) {
                int i = tid + it * 256;
                int d = i >> 3, k8 = (i & 7) * 8;
                *(short8*)(Vs + d * LDS_VROW + k8) =
                    *(const short8*)(vh + gv + (size_t)d * T_ + k8);
            }
        }
        __syncthreads();

        floatx4 s[4];
        #pragma unroll
        for (int kg = 0; kg < 4; kg++) {
            floatx4 acc = {0.f, 0.f, 0.f, 0.f};
            #pragma unroll
            for (int c = 0; c < 4; c++) {
                short8 kf = *(const short8*)(Ks + (kg*16 + n16) * LDS_KROW + c*32 + quad*8);
                acc = __builtin_amdgcn_mfma_f32_16x16x32_bf16(qf[c], kf, acc, 0, 0, 0);
            }
            s[kg] = acc;
        }

        float alpha[4];
        #pragma unroll
        for (int r = 0; r < 4; r++) {
            const int qrow = q0w + quad * 4 + r;
            float v0 = s[0][r], v1 = s[1][r], v2 = s[2][r], v3 = s[3][r];
            if (kv0 +  0 + n16 > qrow) v0 = -INFINITY;
            if (kv0 + 16 + n16 > qrow) v1 = -INFINITY;
            if (kv0 + 32 + n16 > qrow) v2 = -INFINITY;
            if (kv0 + 48 + n16 > qrow) v3 = -INFINITY;

            float tm = fmaxf(fmaxf(v0, v1), fmaxf(v2, v3));
            tm = fmaxf(tm, __shfl_xor(tm, 1));
            tm = fmaxf(tm, __shfl_xor(tm, 2));
            tm = fmaxf(tm, __shfl_xor(tm, 4));
            tm = fmaxf(tm, __shfl_xor(tm, 8));

            const float mnew = fmaxf(mrow[r], tm);
            const float a    = __expf(mrow[r] - mnew);
            const float p0 = __expf(v0 - mnew), p1 = __expf(v1 - mnew);
            const float p2 = __expf(v2 - mnew), p3 = __expf(v3 - mnew);

            float ts = p0 + p1 + p2 + p3;
            ts += __shfl_xor(ts, 1);
            ts += __shfl_xor(ts, 2);
            ts += __shfl_xor(ts, 4);
            ts += __shfl_xor(ts, 8);

            lrow[r] = lrow[r] * a + ts;
            mrow[r] = mnew;
            alpha[r] = a;

            const int prow = (quad * 4 + r) * LDS_PROW;
            Ps[w][prow + n16 +  0] = f2bf(p0);
            Ps[w][prow + n16 + 16] = f2bf(p1);
            Ps[w][prow + n16 + 32] = f2bf(p2);
            Ps[w][prow + n16 + 48] = f2bf(p3);
        }
        #pragma unroll
        for (int nt = 0; nt < 8; nt++)
            #pragma unroll
            for (int r = 0; r < 4; r++) of[nt][r] *= alpha[r];

        short8 pf0 = *(const short8*)(&Ps[w][n16 * LDS_PROW + quad * 8]);
        short8 pf1 = *(const short8*)(&Ps[w][n16 * LDS_PROW + 32 + quad * 8]);
        #pragma unroll
        for (int nt = 0; nt < 8; nt++) {
            short8 vf0 = *(const short8*)(Vs + (nt*16 + n16) * LDS_VROW + quad * 8);
            short8 vf1 = *(const short8*)(Vs + (nt*16 + n16) * LDS_VROW + 32 + quad * 8);
            of[nt] = __builtin_amdgcn_mfma_f32_16x16x32_bf16(pf0, vf0, of[nt], 0, 0, 0);
            of[nt] = __builtin_amdgcn_mfma_f32_16x16x32_bf16(pf1, vf1, of[nt], 0, 0, 0);
        }
    }

    const int b = bh >> 4, h = bh & 15;
    #pragma unroll
    for (int r = 0; r < 4; r++) {
        const float inv = 1.f / lrow[r];
        const size_t orow = ((size_t)b * T_ + q0w + quad*4 + r) * H_ + h * HD_;
        #pragma unroll
        for (int nt = 0; nt < 8; nt++)
            o[orow + nt*16 + n16] = f2bf(of[nt][r] * inv);
    }
}

extern "C" void kernel_launch(void* const* d_in, const int* in_sizes, int n_in,
                              void* d_out, int out_size, void* d_ws, size_t ws_size,
                              hipStream_t stream)
{
    const float* x    = (const float*)d_in[0];
    const float* cosp = (const float*)d_in[1];
    const float* sinp = (const float*)d_in[2];
    const float* Wq   = (const float*)d_in[3];
    const float* Wk   = (const float*)d_in[4];
    const float* Wv   = (const float*)d_in[5];
    const float* Wo   = (const float*)d_in[6];

    const size_t NEL  = (size_t)B_ * T_ * H_;   // 8388608
    const size_t NB   = NEL * 4;                // 33.5 MB
    const int    XN   = (int)NEL;               // x elements
    const int    WN   = H_ * H_;                // 4194304 per weight
    char* ws = (char*)d_ws;

    // overlay plan (total 4*NB = 134 MB, proven footprint):
    unsigned short* xh   = (unsigned short*)(ws);                 // [0, NB/2)
    unsigned short* Woh  = (unsigned short*)(ws + NB/2);          // NB/4
    unsigned short* Wqh  = (unsigned short*)(ws + 3*NB/4);        // NB/4
    unsigned short* Wkh  = (unsigned short*)(ws + NB);            // NB/4
    unsigned short* Wvh  = (unsigned short*)(ws + 5*NB/4);        // NB/4
    unsigned short* qpre = (unsigned short*)(ws + 3*NB/2);        // NB/2
    unsigned short* kpre = (unsigned short*)(ws + 2*NB);          // NB/2
    unsigned short* vpre = (unsigned short*)(ws + 5*NB/2);        // NB/2
    unsigned short* qh   = (unsigned short*)(ws + 3*NB);          // NB/2
    unsigned short* kh   = (unsigned short*)(ws + 7*NB/2);        // NB/2
    unsigned short* vh   = (unsigned short*)(ws);                 // overlays dead xh
    unsigned short* abh  = (unsigned short*)(ws + 3*NB/2);        // overlays dead qpre

    f32_to_bf16<<<XN/1024, 256, 0, stream>>>(x,  xh,  XN);
    f32_to_bf16<<<WN/1024, 256, 0, stream>>>(Wq, Wqh, WN);
    f32_to_bf16<<<WN/1024, 256, 0, stream>>>(Wk, Wkh, WN);
    f32_to_bf16<<<WN/1024, 256, 0, stream>>>(Wv, Wvh, WN);
    f32_to_bf16<<<WN/1024, 256, 0, stream>>>(Wo, Woh, WN);

    const int M = B_ * T_, N = H_, K = H_;
    dim3 gg(N / 128, M / 128);

    gemm_mfma<true><<<gg, 256, 0, stream>>>(xh, Wqh, nullptr, qpre, M, N, K);
    gemm_mfma<true><<<gg, 256, 0, stream>>>(xh, Wkh, nullptr, kpre, M, N, K);
    gemm_mfma<true><<<gg, 256, 0, stream>>>(xh, Wvh, nullptr, vpre, M, N, K);

    rope_convert_qk<<<(B_*T_*NH_*64)/256, 256, 0, stream>>>(qpre, kpre, cosp, sinp, qh, kh);
    transpose_v<<<dim3(T_/64, HD_/64, B_*NH_), 256, 0, stream>>>(vpre, vh);

    attn_mfma<<<dim3(T_/64, B_*NH_), 256, 0, stream>>>(qh, kh, vh, abh);

    gemm_mfma<false><<<gg, 256, 0, stream>>>(abh, Woh, (float*)d_out, nullptr, M, N, K);
}